// Round 15
// baseline (2863.104 us; speedup 1.0000x reference)
//
#include <hip/hip_runtime.h>
#include <hip/hip_fp16.h>
#include <cstddef>

#define Bb 64
#define Tt 512
#define INRAW 225
#define Hh 256
#define G4 1024
#define Ee 512
#define NCODE 128
#define NCLS 250

typedef _Float16 half8_t __attribute__((ext_vector_type(8)));
typedef float f32x4 __attribute__((ext_vector_type(4)));
typedef unsigned u32x4 __attribute__((ext_vector_type(4)));

__device__ __forceinline__ float sigf(float x) { return 1.0f / (1.0f + expf(-x)); }
__device__ __forceinline__ float fsig(float x) { return __builtin_amdgcn_rcpf(1.0f + __expf(-x)); }
__device__ __forceinline__ float ftanh(float x) {
  return 2.0f * __builtin_amdgcn_rcpf(1.0f + __expf(-2.0f * x)) - 1.0f;
}

// packed signed-int16 max (VOP3P); fp16 sentinel 0x7C00 is the int16 max among
// {finite |h|<=1 patterns} ∪ {0x7C00}, so a pk_max fold detects any sentinel.
__device__ __forceinline__ unsigned pkmax16(unsigned a, unsigned b) {
  unsigned r;
  asm("v_pk_max_i16 %0, %1, %2" : "=v"(r) : "v"(a), "v"(b));
  return r;
}

// ------- stride-loop sentinel fill (coherent x4) ------------------------------
__global__ __launch_bounds__(256) void fill_inf4_k(u32x4* __restrict__ p, long n4) {
  long i = (long)blockIdx.x * 256 + threadIdx.x;
  const long stride = (long)gridDim.x * 256;
  u32x4 v = {0x7C007C00u, 0x7C007C00u, 0x7C007C00u, 0x7C007C00u};
  for (; i < n4; i += stride) {
    asm volatile("global_store_dwordx4 %0, %1, off sc0 sc1" :: "v"(p + i), "v"(v) : "memory");
  }
}

// ---- merged prep: [fill hex trio | fill hexBl | conv x | all weight packs] ---
// (fill counts FIXED: R14 used half-counts for u32x4 stores — 2x overrun race)
// block ranges (256 thr each):
//   [0,12288)        fill hex trio: 3*SZ_HEX halfs = 3,145,728 u32x4 stores
//   [+4096)          fill hexBl: 1,048,576 u32x4 stores
//   [+32768)         conv_x_h (8,388,608 elems)
//   [+2048)          pack_w_k dWihB (K=512)
//   [+3072)          pack_w_frag eWhhF/eWhhB/dWhhF
//   [+2048)          pack_wih_frag eWihF/eWihB (KS=8)
//   [+2048)          pack_wih_frag dWihF (KS=16)            total 58368
__global__ __launch_bounds__(256) void prep_all_k(
    u32x4* __restrict__ hexfill, u32x4* __restrict__ hexblfill,
    const float* __restrict__ x, _Float16* __restrict__ xh,
    const float* __restrict__ dWihB, float* __restrict__ wpkbd,
    const float* __restrict__ eWhhF, _Float16* __restrict__ wphF,
    const float* __restrict__ eWhhB, _Float16* __restrict__ wphB,
    const float* __restrict__ dWhhF, _Float16* __restrict__ wphD,
    const float* __restrict__ eWihF, _Float16* __restrict__ wpihF,
    const float* __restrict__ eWihB, _Float16* __restrict__ wpihB,
    const float* __restrict__ dWihF, _Float16* __restrict__ wpihD) {
  int blk = blockIdx.x;
  const int tid = threadIdx.x;
  u32x4 sv = {0x7C007C00u, 0x7C007C00u, 0x7C007C00u, 0x7C007C00u};

  if (blk < 12288) {                       // trio fill (3,145,728 x4)
    long i = (long)blk * 256 + tid;
    asm volatile("global_store_dwordx4 %0, %1, off sc0 sc1"
                 :: "v"(hexfill + i), "v"(sv) : "memory");
    return;
  }
  blk -= 12288;
  if (blk < 4096) {                        // hexBl fill (1,048,576 x4)
    long i = (long)blk * 256 + tid;
    asm volatile("global_store_dwordx4 %0, %1, off sc0 sc1"
                 :: "v"(hexblfill + i), "v"(sv) : "memory");
    return;
  }
  blk -= 4096;
  if (blk < 32768) {                       // conv x -> fp16 padded
    int idx = blk * 256 + tid;
    int row = idx >> 8, k = idx & 255;
    xh[idx] = (k < INRAW) ? (_Float16)x[(size_t)row * INRAW + k] : (_Float16)0.f;
    return;
  }
  blk -= 32768;
  if (blk < 2048) {                        // pack_w_k (dec_bwd fp32 pack, K=512)
    int idx = blk * 256 + tid;
    int jg = idx >> 9;
    int k = idx & 511;
    int j = jg >> 2, g = jg & 3;
    wpkbd[(((size_t)k << 8) + j) * 4 + g] = dWihB[(size_t)(g * 256 + j) * 512 + k];
    return;
  }
  blk -= 2048;
  if (blk < 3072) {                        // 3x pack_w_frag
    const float* W = (blk < 1024) ? eWhhF : (blk < 2048) ? eWhhB : dWhhF;
    _Float16* wp = (blk < 1024) ? wphF : (blk < 2048) ? wphB : wphD;
    int idx = (blk & 1023) * 256 + tid;
    int e = idx & 7, l = (idx >> 3) & 63, zg = (idx >> 9) & 7;
    int ks = (idx >> 12) & 7, wv = (idx >> 15) & 7;
    int z = zg >> 2, g = zg & 3;
    int u = wv * 32 + z * 16 + (l & 15);
    int k = ks * 32 + (l >> 4) * 8 + e;
    wp[idx] = (_Float16)W[(size_t)(g * 256 + u) * 256 + k];
    return;
  }
  blk -= 3072;
  if (blk < 2048) {                        // 2x pack_wih_frag enc (KS=8)
    const float* W = (blk < 1024) ? eWihF : eWihB;
    _Float16* wp = (blk < 1024) ? wpihF : wpihB;
    int idx = (blk & 1023) * 256 + tid;
    int e = idx & 7, l = (idx >> 3) & 63;
    int tail = idx >> 9;
    int ks = tail & 7; tail >>= 3;
    int z = tail & 1, w = (tail >> 1) & 7, g = tail >> 4;
    if (g >= 4) return;
    int k = ks * 32 + (l >> 4) * 8 + e;
    int u = w * 32 + z * 16 + (l & 15);
    wp[idx] = (k < INRAW) ? (_Float16)W[(size_t)(g * 256 + u) * INRAW + k] : (_Float16)0.f;
    return;
  }
  blk -= 2048;
  {                                        // pack_wih_frag dec (KS=16)
    int idx = blk * 256 + tid;
    int e = idx & 7, l = (idx >> 3) & 63;
    int tail = idx >> 9;
    int ks = tail & 15; tail >>= 4;
    int z = tail & 1, w = (tail >> 1) & 7, g = tail >> 4;
    if (g >= 4) return;
    int k = ks * 32 + (l >> 4) * 8 + e;
    int u = w * 32 + z * 16 + (l & 15);
    wpihD[idx] = (_Float16)dWihF[(size_t)(g * 256 + u) * 512 + k];
  }
}

// ---- MFMA input-projection GEMM: pre = A @ Wih^T + bias, fragment-layout out.
// grid (t=512, g=4, zsel); block 256 = 4 waves (batch-group). K = 256 or 512.
__global__ __launch_bounds__(256) void gemm_mfma_pre(const _Float16* __restrict__ Ah,
                                                     const _Float16* __restrict__ Bp0,
                                                     const float* __restrict__ bias0,
                                                     __half* __restrict__ C0,
                                                     const _Float16* __restrict__ Bp1,
                                                     const float* __restrict__ bias1,
                                                     __half* __restrict__ C1, int K) {
  const int t = blockIdx.x, g = blockIdx.y;
  const int zsel = blockIdx.z;
  const _Float16* Bp = zsel ? Bp1 : Bp0;
  const float* bias = zsel ? bias1 : bias0;
  __half* C = zsel ? C1 : C0;
  const int bg = threadIdx.x >> 6;
  const int l = threadIdx.x & 63, l15 = l & 15, lg = l >> 4;
  const int KS = K >> 5;

  f32x4 acc[16];
#pragma unroll
  for (int ct = 0; ct < 16; ++ct) acc[ct] = (f32x4){0.f, 0.f, 0.f, 0.f};

  const _Float16* arow = Ah + ((size_t)(bg * 16 + l15) * 512 + t) * K + lg * 8;

  for (int kh = 0; kh < KS; kh += 8) {
    half8_t af[8];
#pragma unroll
    for (int k2 = 0; k2 < 8; ++k2)
      af[k2] = *(const half8_t*)(arow + (kh + k2) * 32);
#pragma unroll
    for (int ct = 0; ct < 16; ++ct) {
      const int w = ct >> 1, z = ct & 1;
      const _Float16* bb = Bp + ((((size_t)(g * 8 + w) * 2 + z) * KS + kh) * 64 + l) * 8;
#pragma unroll
      for (int k2 = 0; k2 < 8; ++k2) {
        half8_t bf = *(const half8_t*)(bb + (size_t)k2 * 512);
        acc[ct] = __builtin_amdgcn_mfma_f32_16x16x32_f16(af[k2], bf, acc[ct], 0, 0, 0);
      }
    }
  }

#pragma unroll
  for (int ct = 0; ct < 16; ++ct) {
    const int w = ct >> 1, z = ct & 1;
    const int u = w * 32 + z * 16 + l15;
    const float bs = bias[g * 256 + u];
    union { unsigned short us[4]; uint2 u2; } pk;
#pragma unroll
    for (int j = 0; j < 4; ++j) {
      __half hv = __float2half(acc[ct][j] + bs);
      pk.us[j] = *(unsigned short*)&hv;
    }
    __half* dst = C + ((((size_t)t * 4 + bg) * 8 + w) * 2 + z) * 1024 + l * 16 + g * 4;
    *(uint2*)dst = pk.u2;
  }
}

// ------ LSTM scan with XCD-local fast path. blockIdx = slice*8 + group, so all
// 16 slices of a group share an XCD under %8 round-robin. Exchange: sc0 store
// to hexl (XCD L2) + sc0sc1 store to hexg (L3, guaranteed). Consumer polls
// hexl <=4 tries then hexg forever — correct under ANY block->XCD mapping.
__global__ __launch_bounds__(64) void lstm_scan_sync(
    const half8_t* __restrict__ preF, const half8_t* __restrict__ wF,
    _Float16* __restrict__ hexgF, _Float16* __restrict__ hexlF,
    const half8_t* __restrict__ preB, const half8_t* __restrict__ wB,
    _Float16* __restrict__ hexgB, _Float16* __restrict__ hexlB,
    int ngTot) {
  const int group = blockIdx.x & 7;
  const int sl = blockIdx.x >> 3;
  if (group >= ngTot) return;
  const int isB = (group >= 4) ? 1 : 0;
  const int rg = group & 3;
  const half8_t* pre = isB ? preB : preF;
  const half8_t* wfrag = isB ? wB : wF;
  _Float16* hexg = isB ? hexgB : hexgF;
  _Float16* hexl = isB ? hexlB : hexlF;
  const int w_ = sl >> 1, z_ = sl & 1;
  const int l = threadIdx.x, l15 = l & 15, lg = l >> 4;
  const int u0 = sl * 16;

  half8_t bfr[8][4];
#pragma unroll
  for (int ks = 0; ks < 8; ++ks)
#pragma unroll
    for (int g = 0; g < 4; ++g)
      bfr[ks][g] = wfrag[(size_t)((w_ * 8 + ks) * 8 + z_ * 4 + g) * 64 + l];

  float c[4] = {0.f, 0.f, 0.f, 0.f};
  half8_t pc0, pc1;
  {
    const int t0 = isB ? (Tt - 1) : 0;
    const half8_t* pp = pre + ((size_t)(t0 * 4 + rg) * 16 + sl) * 128 + l * 2;
    pc0 = pp[0]; pc1 = pp[1];
  }

  for (int s = 0; s < Tt; ++s) {
    f32x4 acc[4];
#pragma unroll
    for (int g = 0; g < 4; ++g)
#pragma unroll
      for (int j = 0; j < 4; ++j)
        acc[g][j] = (float)((g < 2 ? pc0 : pc1)[(g & 1) * 4 + j]);

    if (s + 1 < Tt) {
      const int tn = isB ? (Tt - 2 - s) : (s + 1);
      const half8_t* pp = pre + ((size_t)(tn * 4 + rg) * 16 + sl) * 128 + l * 2;
      pc0 = pp[0]; pc1 = pp[1];
    }

    if (s > 0) {
      const size_t boff = (((size_t)(s - 1) * 64 + rg * 16) * 256) * 2;
      const char* abl = (const char*)hexl + boff;
      const char* abg = (const char*)hexg + boff;
      half8_t afr[8];
      int ok = 0;
      for (int tr = 0; tr < 4; ++tr) {          // fast path: XCD-local L2
#pragma unroll
        for (int ks = 0; ks < 8; ++ks) {
          const void* ap = (const void*)(abl + l15 * 512 + ks * 64 + lg * 16);
          asm volatile("global_load_dwordx4 %0, %1, off sc0"
                       : "=v"(afr[ks]) : "v"(ap) : "memory");
        }
        asm volatile("s_waitcnt vmcnt(0)" ::: "memory");
        union HU { half8_t h; u32x4 u; } cu;
        cu.h = afr[0];
        unsigned mm = pkmax16(pkmax16(cu.u[0], cu.u[1]), pkmax16(cu.u[2], cu.u[3]));
#pragma unroll
        for (int ks = 1; ks < 8; ++ks) {
          cu.h = afr[ks];
          mm = pkmax16(mm, pkmax16(pkmax16(cu.u[0], cu.u[1]), pkmax16(cu.u[2], cu.u[3])));
        }
        int bad = ((mm & 0xFFFFu) == 0x7C00u) || ((mm >> 16) == 0x7C00u);
        if (__all(!bad)) { ok = 1; break; }
      }
      if (!ok) {                                // guaranteed path: L3 coherent
        while (true) {
#pragma unroll
          for (int ks = 0; ks < 8; ++ks) {
            const void* ap = (const void*)(abg + l15 * 512 + ks * 64 + lg * 16);
            asm volatile("global_load_dwordx4 %0, %1, off sc0 sc1"
                         : "=v"(afr[ks]) : "v"(ap) : "memory");
          }
          asm volatile("s_waitcnt vmcnt(0)" ::: "memory");
          union HU { half8_t h; u32x4 u; } cu;
          cu.h = afr[0];
          unsigned mm = pkmax16(pkmax16(cu.u[0], cu.u[1]), pkmax16(cu.u[2], cu.u[3]));
#pragma unroll
          for (int ks = 1; ks < 8; ++ks) {
            cu.h = afr[ks];
            mm = pkmax16(mm, pkmax16(pkmax16(cu.u[0], cu.u[1]), pkmax16(cu.u[2], cu.u[3])));
          }
          int bad = ((mm & 0xFFFFu) == 0x7C00u) || ((mm >> 16) == 0x7C00u);
          if (__all(!bad)) break;
        }
      }
      __builtin_amdgcn_sched_barrier(0);

#pragma unroll
      for (int ks = 0; ks < 8; ++ks)
#pragma unroll
        for (int g = 0; g < 4; ++g)
          acc[g] = __builtin_amdgcn_mfma_f32_16x16x32_f16(afr[ks], bfr[ks][g], acc[g], 0, 0, 0);
    }

    // gates -> c,h; publish: local (sc0, fast) then global (sc0 sc1, guaranteed)
#pragma unroll
    for (int j = 0; j < 4; ++j) {
      float iv = fsig(acc[0][j]);
      float fv = fsig(acc[1][j]);
      float gv = ftanh(acc[2][j]);
      float ov = fsig(acc[3][j]);
      c[j] = fv * c[j] + iv * gv;
      float hv = ov * ftanh(c[j]);
      union { _Float16 f; unsigned short u; } cv;
      cv.f = (_Float16)hv;
      unsigned hb32 = cv.u;
      const size_t hidx = ((size_t)s * 64 + rg * 16 + lg * 4 + j) * 256 + u0 + l15;
      asm volatile("global_store_short %0, %1, off sc0"
                   :: "v"((const void*)(hexl + hidx)), "v"(hb32) : "memory");
      asm volatile("global_store_short %0, %1, off sc0 sc1"
                   :: "v"((const void*)(hexg + hidx)), "v"(hb32) : "memory");
    }
  }
}

// ---------------- VQ: 4 vectors/block, 128 threads; writes qh fp16 ------------
#define VPB 4
__global__ __launch_bounds__(128) void vq_kernel(const _Float16* __restrict__ hexF,
                                                 const _Float16* __restrict__ hexB,
                                                 const float* __restrict__ cb,
                                                 _Float16* __restrict__ qh,
                                                 float* __restrict__ dmin) {
  const int tid = threadIdx.x;
  const int v0 = blockIdx.x * VPB;
  __shared__ __align__(16) float zs[VPB][Ee];
  __shared__ float dsh[NCODE];
  __shared__ int ish[NCODE];
  __shared__ int best[VPB];

#pragma unroll
  for (int v = 0; v < VPB; ++v) {
    const int vv = v0 + v;
    const int b = vv >> 9, t = vv & 511;
    const _Float16* hf = hexF + ((size_t)t * 64 + b) * 256;
    const _Float16* hb = hexB + ((size_t)(Tt - 1 - t) * 64 + b) * 256;
    zs[v][tid]       = (float)hf[tid];
    zs[v][tid + 128] = (float)hf[tid + 128];
    zs[v][tid + 256] = (float)hb[tid];
    zs[v][tid + 384] = (float)hb[tid + 128];
  }
  __syncthreads();

  float dv[VPB] = {0.0f, 0.0f, 0.0f, 0.0f};
  const float4* crow = (const float4*)(cb + (size_t)tid * Ee);
#pragma unroll 2
  for (int e4 = 0; e4 < Ee / 4; ++e4) {
    float4 cc = crow[e4];
#pragma unroll
    for (int v = 0; v < VPB; ++v) {
      float4 z = *(const float4*)&zs[v][e4 * 4];
      float t0 = z.x - cc.x, t1 = z.y - cc.y, t2 = z.z - cc.z, t3 = z.w - cc.w;
      dv[v] = fmaf(t0, t0, dv[v]);
      dv[v] = fmaf(t1, t1, dv[v]);
      dv[v] = fmaf(t2, t2, dv[v]);
      dv[v] = fmaf(t3, t3, dv[v]);
    }
  }

#pragma unroll
  for (int v = 0; v < VPB; ++v) {
    __syncthreads();
    dsh[tid] = dv[v];
    ish[tid] = tid;
    __syncthreads();
    for (int off = 64; off > 0; off >>= 1) {
      if (tid < off) {
        float dn = dsh[tid + off];
        int in_ = ish[tid + off];
        if (dn < dsh[tid] || (dn == dsh[tid] && in_ < ish[tid])) {
          dsh[tid] = dn;
          ish[tid] = in_;
        }
      }
      __syncthreads();
    }
    if (tid == 0) {
      best[v] = ish[0];
      dmin[v0 + v] = dsh[0];
    }
  }
  __syncthreads();

#pragma unroll
  for (int v = 0; v < VPB; ++v) {
    const float* cbest = cb + (size_t)best[v] * Ee;
    _Float16* qrow = qh + (size_t)(v0 + v) * Ee;
#pragma unroll
    for (int u = 0; u < 4; ++u) {
      int e = tid + u * 128;
      float z = zs[v][e];
      qrow[e] = (_Float16)(z + (cbest[e] - z));
    }
  }
}

// ---------------- vq loss reduce (1024 threads) ----------------
__global__ __launch_bounds__(1024) void vq_reduce(const float* __restrict__ dmin,
                                                  float* __restrict__ out) {
  __shared__ float sh[1024];
  int tid = threadIdx.x;
  float s = 0.0f;
  for (int i = tid; i < Bb * Tt; i += 1024) s += dmin[i];
  sh[tid] = s;
  __syncthreads();
  for (int off = 512; off > 0; off >>= 1) {
    if (tid < off) sh[tid] += sh[tid + off];
    __syncthreads();
  }
  if (tid == 0) out[Bb * NCLS] = sh[0] * (1.25f / ((float)(Bb * Tt) * (float)Ee));
}

// ---------------- decoder backward, single step at t=T-1 (h_prev=c_prev=0) ----
__global__ __launch_bounds__(256) void dec_bwd_last(const _Float16* __restrict__ qh,
                                                    const float* __restrict__ wpB,
                                                    const float* __restrict__ bias,
                                                    float* __restrict__ hb_last) {
  int b = blockIdx.x, tid = threadIdx.x;
  __shared__ __align__(16) float zsl[Ee];
  const _Float16* qrow = qh + ((size_t)b * Tt + (Tt - 1)) * Ee;
  zsl[tid] = (float)qrow[tid];
  zsl[tid + 256] = (float)qrow[tid + 256];
  __syncthreads();
  float a0 = bias[tid], a1 = bias[256 + tid], a2 = bias[512 + tid], a3 = bias[768 + tid];
  const float4* wp4 = (const float4*)wpB;
#pragma unroll 4
  for (int k = 0; k < Ee; ++k) {
    float zk = zsl[k];
    float4 w = wp4[((size_t)k << 8) + tid];
    a0 = fmaf(zk, w.x, a0); a1 = fmaf(zk, w.y, a1);
    a2 = fmaf(zk, w.z, a2); a3 = fmaf(zk, w.w, a3);
  }
  float i = sigf(a0), f = sigf(a1), g = tanhf(a2), o = sigf(a3);
  (void)f;
  float cc = i * g;
  hb_last[b * Hh + tid] = o * tanhf(cc);
}

// ---------------- classifier ----------------
__global__ __launch_bounds__(256) void classifier_k(const _Float16* __restrict__ hexD,
                                                    const float* __restrict__ hb_last,
                                                    const float* __restrict__ Wcls,
                                                    const float* __restrict__ bcls,
                                                    float* __restrict__ out) {
  int b = blockIdx.x, tid = threadIdx.x;
  __shared__ __align__(16) float dl[Ee];
  dl[tid] = (float)hexD[((size_t)(Tt - 1) * 64 + b) * 256 + tid];
  dl[tid + 256] = hb_last[b * Hh + tid];
  __syncthreads();
  if (tid < NCLS) {
    const float4* wr = (const float4*)(Wcls + (size_t)tid * Ee);
    float acc = bcls[tid];
#pragma unroll 4
    for (int e4 = 0; e4 < Ee / 4; ++e4) {
      float4 w = wr[e4];
      float4 z = *(const float4*)&dl[e4 * 4];
      acc = fmaf(w.x, z.x, acc);
      acc = fmaf(w.y, z.y, acc);
      acc = fmaf(w.z, z.z, acc);
      acc = fmaf(w.w, z.w, acc);
    }
    out[b * NCLS + tid] = acc;
  }
}

// ---------------- launch ----------------
extern "C" void kernel_launch(void* const* d_in, const int* in_sizes, int n_in,
                              void* d_out, int out_size, void* d_ws, size_t ws_size,
                              hipStream_t stream) {
  const float* x     = (const float*)d_in[0];
  const float* eWihF = (const float*)d_in[1];
  const float* eWhhF = (const float*)d_in[2];
  const float* ebF   = (const float*)d_in[3];
  const float* eWihB = (const float*)d_in[4];
  const float* eWhhB = (const float*)d_in[5];
  const float* ebB   = (const float*)d_in[6];
  const float* cb    = (const float*)d_in[7];
  const float* dWihF = (const float*)d_in[8];
  const float* dWhhF = (const float*)d_in[9];
  const float* dbF   = (const float*)d_in[10];
  const float* dWihB = (const float*)d_in[11];
  // d_in[12] = dec_Whh_b: unused (backward decoder state at t=T-1 starts from zero)
  const float* dbB   = (const float*)d_in[13];
  const float* Wcls  = (const float*)d_in[14];
  const float* bcls  = (const float*)d_in[15];
  float* out = (float*)d_out;
  float* w = (float*)d_ws;

  const size_t MR = (size_t)Bb * Tt;                 // 32768
  const size_t SZ_PRE_H = MR * G4 / 2;               // fp16 pre buffer, float units
  const size_t SZ_HEX  = (size_t)Tt * Bb * Hh / 2;   // fp16 exchange, float units
  const size_t SZ_XH   = MR * 256 / 2;               // xh fp16 (== SZ_HEX)
  const size_t SZ_WPK  = (size_t)512 * G4;           // dec_bwd fp32 pack
  const size_t SZ_WPH  = (size_t)G4 * Hh / 2;        // Whh frag pack, float units
  const size_t SZ_WIH  = (size_t)4 * 8 * 2 * 8 * 64 * 8 / 2;   // 131072 (enc, KS=8)
  const size_t SZ_WIHD = SZ_WIH * 2;                 // dec, KS=16

  size_t o = 0;
  __half* preFh = (__half*)(w + o); o += SZ_PRE_H;
  __half* preBh = (__half*)(w + o); o += SZ_PRE_H;
  _Float16* hexF = (_Float16*)(w + o); o += SZ_HEX;
  _Float16* hexB = (_Float16*)(w + o); o += SZ_HEX;
  _Float16* hexD = (_Float16*)(w + o); o += SZ_HEX;
  _Float16* xh = (_Float16*)(w + o); o += SZ_XH;
  _Float16* hexBl = (_Float16*)(w + o); o += SZ_HEX;   // local exchange (bwd enc)
  float* wpkbd = w + o; o += SZ_WPK;
  _Float16* wphF = (_Float16*)(w + o); o += SZ_WPH;
  _Float16* wphB = (_Float16*)(w + o); o += SZ_WPH;
  _Float16* wphD = (_Float16*)(w + o); o += SZ_WPH;
  _Float16* wpihF = (_Float16*)(w + o); o += SZ_WIH;
  _Float16* wpihB = (_Float16*)(w + o); o += SZ_WIH;
  _Float16* wpihD = (_Float16*)(w + o); o += SZ_WIHD;
  float* dminp = w + o; o += MR;
  float* hbl   = w + o; o += (size_t)Bb * Hh;
  // aliases over dead regions
  _Float16* qh = (_Float16*)preFh;    // fp16 quant over dead enc preF (post-scan)
  __half* dprf = preBh;               // dec fp16 pre over dead enc preB
  _Float16* hexFl = xh;               // local exchange (fwd enc) over dead xh
  _Float16* hexDl = hexBl;            // local exchange (dec) over dead hexBl

  // 1. merged prep: sentinel fills + x conv + all weight packs (one dispatch)
  hipLaunchKernelGGL(prep_all_k, dim3(58368), dim3(256), 0, stream,
                     (u32x4*)hexF, (u32x4*)hexBl, x, xh,
                     dWihB, wpkbd,
                     eWhhF, wphF, eWhhB, wphB, dWhhF, wphD,
                     eWihF, wpihF, eWihB, wpihB, dWihF, wpihD);

  // 2. encoder input projections (MFMA, both directions in one dispatch)
  hipLaunchKernelGGL(gemm_mfma_pre, dim3(Tt, 4, 2), dim3(256), 0, stream,
                     xh, wpihF, ebF, preFh, wpihB, ebB, preBh, 256);

  // 2b. sentinel-fill hexFl (alias over xh, now dead)
  hipLaunchKernelGGL(fill_inf4_k, dim3(2048), dim3(256), 0, stream,
                     (u32x4*)hexFl, (long)(SZ_HEX / 4));

  // 3. encoder scan: 128 blocks, blockIdx = slice*8 + group (XCD grouping)
  hipLaunchKernelGGL(lstm_scan_sync, dim3(128), dim3(64), 0, stream,
                     (const half8_t*)preFh, (const half8_t*)wphF, hexF, hexFl,
                     (const half8_t*)preBh, (const half8_t*)wphB, hexB, hexBl, 8);

  // 4. VQ + loss (reads global hex; writes qh fp16 over dead preF)
  hipLaunchKernelGGL(vq_kernel, dim3((int)(MR / VPB)), dim3(128), 0, stream,
                     hexF, hexB, cb, qh, dminp);
  hipLaunchKernelGGL(vq_reduce, dim3(1), dim3(1024), 0, stream, dminp, out);

  // 4b. sentinel-refill hexDl (alias over hexBl, enc scan done)
  hipLaunchKernelGGL(fill_inf4_k, dim3(2048), dim3(256), 0, stream,
                     (u32x4*)hexDl, (long)(SZ_HEX / 4));

  // 5. decoder fwd input projection (MFMA, K=512)
  hipLaunchKernelGGL(gemm_mfma_pre, dim3(Tt, 4, 1), dim3(256), 0, stream,
                     qh, wpihD, dbF, dprf, wpihD, dbF, dprf, 512);

  // 6. decoder bwd (only t=T-1 contributes)
  hipLaunchKernelGGL(dec_bwd_last, dim3(Bb), dim3(256), 0, stream, qh, wpkbd, dbB, hbl);

  // 7. decoder fwd scan: groups 0..3 valid (64 active blocks)
  hipLaunchKernelGGL(lstm_scan_sync, dim3(128), dim3(64), 0, stream,
                     (const half8_t*)dprf, (const half8_t*)wphD, hexD, hexDl,
                     (const half8_t*)dprf, (const half8_t*)wphD, hexD, hexDl, 4);

  // 8. classifier
  hipLaunchKernelGGL(classifier_k, dim3(Bb), dim3(256), 0, stream,
                     hexD, hbl, Wcls, bcls, out);
}

// Round 17
// 2397.122 us; speedup vs baseline: 1.1944x; 1.1944x over previous
//
#include <hip/hip_runtime.h>
#include <hip/hip_fp16.h>
#include <cstddef>

#define Bb 64
#define Tt 512
#define INRAW 225
#define Hh 256
#define G4 1024
#define Ee 512
#define NCODE 128
#define NCLS 250

typedef _Float16 half8_t __attribute__((ext_vector_type(8)));
typedef _Float16 half4_t __attribute__((ext_vector_type(4)));
typedef float f32x4 __attribute__((ext_vector_type(4)));
typedef unsigned u32x4 __attribute__((ext_vector_type(4)));

__device__ __forceinline__ float sigf(float x) { return 1.0f / (1.0f + expf(-x)); }
__device__ __forceinline__ float fsig(float x) { return __builtin_amdgcn_rcpf(1.0f + __expf(-x)); }
__device__ __forceinline__ float ftanh(float x) {
  return 2.0f * __builtin_amdgcn_rcpf(1.0f + __expf(-2.0f * x)) - 1.0f;
}

// packed signed-int16 max (VOP3P); fp16 sentinel 0x7C00 is the int16 max among
// {finite |h|<=1 patterns} ∪ {0x7C00}, so a pk_max fold detects any sentinel.
__device__ __forceinline__ unsigned pkmax16(unsigned a, unsigned b) {
  unsigned r;
  asm("v_pk_max_i16 %0, %1, %2" : "=v"(r) : "v"(a), "v"(b));
  return r;
}

// ---- merged prep: fills + x conv + code projections + weight packs ----------
__global__ __launch_bounds__(256) void prep_all_k(
    u32x4* __restrict__ hexfill,
    const float* __restrict__ x, _Float16* __restrict__ xh,
    const float* __restrict__ cb,
    const float* __restrict__ dWihF, const float* __restrict__ dbF,
    _Float16* __restrict__ projFh,
    const float* __restrict__ dWihB, const float* __restrict__ dbB,
    float* __restrict__ projBf,
    const float* __restrict__ eWhhF, _Float16* __restrict__ wphF,
    const float* __restrict__ eWhhB, _Float16* __restrict__ wphB,
    const float* __restrict__ dWhhF, _Float16* __restrict__ wphD,
    const float* __restrict__ eWihF, _Float16* __restrict__ wpihF,
    const float* __restrict__ eWihB, _Float16* __restrict__ wpihB) {
  int blk = blockIdx.x;
  const int tid = threadIdx.x;

  if (blk < 12288) {                       // trio fill (3,145,728 x4 stores)
    long i = (long)blk * 256 + tid;
    u32x4 sv = {0x7C007C00u, 0x7C007C00u, 0x7C007C00u, 0x7C007C00u};
    asm volatile("global_store_dwordx4 %0, %1, off sc0 sc1"
                 :: "v"(hexfill + i), "v"(sv) : "memory");
    return;
  }
  blk -= 12288;
  if (blk < 32768) {                       // conv x -> fp16 padded
    int idx = blk * 256 + tid;
    int row = idx >> 8, k = idx & 255;
    xh[idx] = (k < INRAW) ? (_Float16)x[(size_t)row * INRAW + k] : (_Float16)0.f;
    return;
  }
  blk -= 32768;
  if (blk < 512) {                         // projF (dec fwd), fp16 frag layout
    int n = (blk & 3) * 256 + tid;         // gate column 0..1023
    int code = blk >> 2;
    const float4* cr = (const float4*)(cb + (size_t)code * Ee);
    const float4* wr = (const float4*)(dWihF + (size_t)n * Ee);
    float acc = 0.f;
#pragma unroll 4
    for (int e4 = 0; e4 < Ee / 4; ++e4) {
      float4 cv = cr[e4], wv = wr[e4];
      acc = fmaf(cv.x, wv.x, acc); acc = fmaf(cv.y, wv.y, acc);
      acc = fmaf(cv.z, wv.z, acc); acc = fmaf(cv.w, wv.w, acc);
    }
    int g = n >> 8, u = n & 255;
    projFh[(size_t)code * 1024 + u * 4 + g] = (_Float16)(acc + dbF[n]);
    return;
  }
  blk -= 512;
  if (blk < 512) {                         // projB (dec bwd), fp32 [code][n]
    int n = (blk & 3) * 256 + tid;
    int code = blk >> 2;
    const float4* cr = (const float4*)(cb + (size_t)code * Ee);
    const float4* wr = (const float4*)(dWihB + (size_t)n * Ee);
    float acc = 0.f;
#pragma unroll 4
    for (int e4 = 0; e4 < Ee / 4; ++e4) {
      float4 cv = cr[e4], wv = wr[e4];
      acc = fmaf(cv.x, wv.x, acc); acc = fmaf(cv.y, wv.y, acc);
      acc = fmaf(cv.z, wv.z, acc); acc = fmaf(cv.w, wv.w, acc);
    }
    projBf[(size_t)code * 1024 + n] = acc + dbB[n];
    return;
  }
  blk -= 512;
  if (blk < 3072) {                        // 3x pack_w_frag
    const float* W = (blk < 1024) ? eWhhF : (blk < 2048) ? eWhhB : dWhhF;
    _Float16* wp = (blk < 1024) ? wphF : (blk < 2048) ? wphB : wphD;
    int idx = (blk & 1023) * 256 + tid;
    int e = idx & 7, l = (idx >> 3) & 63, zg = (idx >> 9) & 7;
    int ks = (idx >> 12) & 7, wv = (idx >> 15) & 7;
    int z = zg >> 2, g = zg & 3;
    int u = wv * 32 + z * 16 + (l & 15);
    int k = ks * 32 + (l >> 4) * 8 + e;
    wp[idx] = (_Float16)W[(size_t)(g * 256 + u) * 256 + k];
    return;
  }
  blk -= 3072;
  {                                        // 2x pack_wih_frag enc (KS=8)
    const float* W = (blk < 1024) ? eWihF : eWihB;
    _Float16* wp = (blk < 1024) ? wpihF : wpihB;
    int idx = (blk & 1023) * 256 + tid;
    int e = idx & 7, l = (idx >> 3) & 63;
    int tail = idx >> 9;
    int ks = tail & 7; tail >>= 3;
    int z = tail & 1, w = (tail >> 1) & 7, g = tail >> 4;
    if (g >= 4) return;
    int k = ks * 32 + (l >> 4) * 8 + e;
    int u = w * 32 + z * 16 + (l & 15);
    wp[idx] = (k < INRAW) ? (_Float16)W[(size_t)(g * 256 + u) * INRAW + k] : (_Float16)0.f;
  }
}

// ---- MFMA input-projection GEMM (encoder): pre = A @ Wih^T + bias ----------
__global__ __launch_bounds__(256) void gemm_mfma_pre(const _Float16* __restrict__ Ah,
                                                     const _Float16* __restrict__ Bp0,
                                                     const float* __restrict__ bias0,
                                                     __half* __restrict__ C0,
                                                     const _Float16* __restrict__ Bp1,
                                                     const float* __restrict__ bias1,
                                                     __half* __restrict__ C1, int K) {
  const int t = blockIdx.x, g = blockIdx.y;
  const int zsel = blockIdx.z;
  const _Float16* Bp = zsel ? Bp1 : Bp0;
  const float* bias = zsel ? bias1 : bias0;
  __half* C = zsel ? C1 : C0;
  const int bg = threadIdx.x >> 6;
  const int l = threadIdx.x & 63, l15 = l & 15, lg = l >> 4;
  const int KS = K >> 5;

  f32x4 acc[16];
#pragma unroll
  for (int ct = 0; ct < 16; ++ct) acc[ct] = (f32x4){0.f, 0.f, 0.f, 0.f};

  const _Float16* arow = Ah + ((size_t)(bg * 16 + l15) * 512 + t) * K + lg * 8;

  for (int kh = 0; kh < KS; kh += 8) {
    half8_t af[8];
#pragma unroll
    for (int k2 = 0; k2 < 8; ++k2)
      af[k2] = *(const half8_t*)(arow + (kh + k2) * 32);
#pragma unroll
    for (int ct = 0; ct < 16; ++ct) {
      const int w = ct >> 1, z = ct & 1;
      const _Float16* bb = Bp + ((((size_t)(g * 8 + w) * 2 + z) * KS + kh) * 64 + l) * 8;
#pragma unroll
      for (int k2 = 0; k2 < 8; ++k2) {
        half8_t bf = *(const half8_t*)(bb + (size_t)k2 * 512);
        acc[ct] = __builtin_amdgcn_mfma_f32_16x16x32_f16(af[k2], bf, acc[ct], 0, 0, 0);
      }
    }
  }

#pragma unroll
  for (int ct = 0; ct < 16; ++ct) {
    const int w = ct >> 1, z = ct & 1;
    const int u = w * 32 + z * 16 + l15;
    const float bs = bias[g * 256 + u];
    union { unsigned short us[4]; uint2 u2; } pk;
#pragma unroll
    for (int j = 0; j < 4; ++j) {
      __half hv = __float2half(acc[ct][j] + bs);
      pk.us[j] = *(unsigned short*)&hv;
    }
    __half* dst = C + ((((size_t)t * 4 + bg) * 8 + w) * 2 + z) * 1024 + l * 16 + g * 4;
    *(uint2*)dst = pk.u2;
  }
}

// ------ multi-block LSTM scan (R10, proven): 1 wave/block, 16u x 16r.
// Sync = sentinel-poll on the data itself (no flags, no fences).
__global__ __launch_bounds__(64) void lstm_scan_sync(
    const half8_t* __restrict__ preF, const half8_t* __restrict__ wF,
    _Float16* __restrict__ hexF,
    const half8_t* __restrict__ preB, const half8_t* __restrict__ wB,
    _Float16* __restrict__ hexB, int nfwd) {
  const int isB = (blockIdx.x >= nfwd) ? 1 : 0;
  const half8_t* pre = isB ? preB : preF;
  const half8_t* wfrag = isB ? wB : wF;
  _Float16* hex = isB ? hexB : hexF;
  const int bid = blockIdx.x - (isB ? nfwd : 0);
  const int rg = bid >> 4, sl = bid & 15;
  const int w_ = sl >> 1, z_ = sl & 1;
  const int l = threadIdx.x, l15 = l & 15, lg = l >> 4;
  const int u0 = sl * 16;

  half8_t bfr[8][4];
#pragma unroll
  for (int ks = 0; ks < 8; ++ks)
#pragma unroll
    for (int g = 0; g < 4; ++g)
      bfr[ks][g] = wfrag[(size_t)((w_ * 8 + ks) * 8 + z_ * 4 + g) * 64 + l];

  float c[4] = {0.f, 0.f, 0.f, 0.f};
  half8_t pc0, pc1;
  {
    const int t0 = isB ? (Tt - 1) : 0;
    const half8_t* pp = pre + ((size_t)(t0 * 4 + rg) * 16 + sl) * 128 + l * 2;
    pc0 = pp[0]; pc1 = pp[1];
  }

  for (int s = 0; s < Tt; ++s) {
    f32x4 acc[4];
#pragma unroll
    for (int g = 0; g < 4; ++g)
#pragma unroll
      for (int j = 0; j < 4; ++j)
        acc[g][j] = (float)((g < 2 ? pc0 : pc1)[(g & 1) * 4 + j]);

    if (s + 1 < Tt) {
      const int tn = isB ? (Tt - 2 - s) : (s + 1);
      const half8_t* pp = pre + ((size_t)(tn * 4 + rg) * 16 + sl) * 128 + l * 2;
      pc0 = pp[0]; pc1 = pp[1];
    }

    if (s > 0) {
      const char* ab = (const char*)hex + (((size_t)(s - 1) * 64 + rg * 16) * 256) * 2;
      half8_t afr[8];
      while (true) {
#pragma unroll
        for (int ks = 0; ks < 8; ++ks) {
          const void* ap = (const void*)(ab + l15 * 512 + ks * 64 + lg * 16);
          asm volatile("global_load_dwordx4 %0, %1, off sc0 sc1"
                       : "=v"(afr[ks]) : "v"(ap) : "memory");
        }
        asm volatile("s_waitcnt vmcnt(0)" ::: "memory");
        union HU { half8_t h; u32x4 u; } cu;
        cu.h = afr[0];
        unsigned mm = pkmax16(pkmax16(cu.u[0], cu.u[1]), pkmax16(cu.u[2], cu.u[3]));
#pragma unroll
        for (int ks = 1; ks < 8; ++ks) {
          cu.h = afr[ks];
          mm = pkmax16(mm, pkmax16(pkmax16(cu.u[0], cu.u[1]), pkmax16(cu.u[2], cu.u[3])));
        }
        int bad = ((mm & 0xFFFFu) == 0x7C00u) || ((mm >> 16) == 0x7C00u);
        if (__all(!bad)) break;
      }
      __builtin_amdgcn_sched_barrier(0);

#pragma unroll
      for (int ks = 0; ks < 8; ++ks)
#pragma unroll
        for (int g = 0; g < 4; ++g)
          acc[g] = __builtin_amdgcn_mfma_f32_16x16x32_f16(afr[ks], bfr[ks][g], acc[g], 0, 0, 0);
    }

#pragma unroll
    for (int j = 0; j < 4; ++j) {
      float iv = fsig(acc[0][j]);
      float fv = fsig(acc[1][j]);
      float gv = ftanh(acc[2][j]);
      float ov = fsig(acc[3][j]);
      c[j] = fv * c[j] + iv * gv;
      float hv = ov * ftanh(c[j]);
      union { _Float16 f; unsigned short u; } cv;
      cv.f = (_Float16)hv;
      unsigned hb32 = cv.u;
      const void* hp = (const void*)(hex + ((size_t)s * 64 + rg * 16 + lg * 4 + j) * 256
                                     + u0 + l15);
      asm volatile("global_store_short %0, %1, off sc0 sc1"
                   :: "v"(hp), "v"(hb32) : "memory");
    }
  }
}

// ---------------- VQ: 4 vectors/block, 128 threads; writes idx + dmin ---------
// hexB is STEP-indexed: backward-direction time t lives at slot Tt-1-t.
#define VPB 4
__global__ __launch_bounds__(128) void vq_kernel(const _Float16* __restrict__ hexF,
                                                 const _Float16* __restrict__ hexB,
                                                 const float* __restrict__ cb,
                                                 int* __restrict__ idxOut,
                                                 float* __restrict__ dmin) {
  const int tid = threadIdx.x;
  const int v0 = blockIdx.x * VPB;
  __shared__ __align__(16) float zs[VPB][Ee];
  __shared__ float dsh[NCODE];
  __shared__ int ish[NCODE];

#pragma unroll
  for (int v = 0; v < VPB; ++v) {
    const int vv = v0 + v;
    const int b = vv >> 9, t = vv & 511;
    const _Float16* hf = hexF + ((size_t)t * 64 + b) * 256;
    const _Float16* hb = hexB + ((size_t)(Tt - 1 - t) * 64 + b) * 256;   // time-reversed
    zs[v][tid]       = (float)hf[tid];
    zs[v][tid + 128] = (float)hf[tid + 128];
    zs[v][tid + 256] = (float)hb[tid];
    zs[v][tid + 384] = (float)hb[tid + 128];
  }
  __syncthreads();

  float dv[VPB] = {0.0f, 0.0f, 0.0f, 0.0f};
  const float4* crow = (const float4*)(cb + (size_t)tid * Ee);
#pragma unroll 2
  for (int e4 = 0; e4 < Ee / 4; ++e4) {
    float4 cc = crow[e4];
#pragma unroll
    for (int v = 0; v < VPB; ++v) {
      float4 z = *(const float4*)&zs[v][e4 * 4];
      float t0 = z.x - cc.x, t1 = z.y - cc.y, t2 = z.z - cc.z, t3 = z.w - cc.w;
      dv[v] = fmaf(t0, t0, dv[v]);
      dv[v] = fmaf(t1, t1, dv[v]);
      dv[v] = fmaf(t2, t2, dv[v]);
      dv[v] = fmaf(t3, t3, dv[v]);
    }
  }

#pragma unroll
  for (int v = 0; v < VPB; ++v) {
    __syncthreads();
    dsh[tid] = dv[v];
    ish[tid] = tid;
    __syncthreads();
    for (int off = 64; off > 0; off >>= 1) {
      if (tid < off) {
        float dn = dsh[tid + off];
        int in_ = ish[tid + off];
        if (dn < dsh[tid] || (dn == dsh[tid] && in_ < ish[tid])) {
          dsh[tid] = dn;
          ish[tid] = in_;
        }
      }
      __syncthreads();
    }
    if (tid == 0) {
      idxOut[v0 + v] = ish[0];
      dmin[v0 + v] = dsh[0];
    }
  }
}

// ---- gather dec pre from per-code projections (fragment layout, bias baked) --
// grid 512 (t), block 256 (4 waves: wave = batch-group b_).
__global__ __launch_bounds__(256) void gather_pre_k(const int* __restrict__ idx,
                                                    const _Float16* __restrict__ projFh,
                                                    __half* __restrict__ C) {
  const int t = blockIdx.x;
  const int b_ = threadIdx.x >> 6;
  const int l = threadIdx.x & 63, l15 = l & 15, lg = l >> 4;

  int cj[4];
#pragma unroll
  for (int j = 0; j < 4; ++j)
    cj[j] = idx[(size_t)(b_ * 16 + lg * 4 + j) * 512 + t];

#pragma unroll
  for (int w_ = 0; w_ < 8; ++w_) {
#pragma unroll
    for (int z_ = 0; z_ < 2; ++z_) {
      const int u = w_ * 32 + z_ * 16 + l15;
      half4_t pv[4];
#pragma unroll
      for (int j = 0; j < 4; ++j)
        pv[j] = *(const half4_t*)(projFh + (size_t)cj[j] * 1024 + u * 4);
      union { _Float16 h[16]; u32x4 q[2]; } outv;
#pragma unroll
      for (int g = 0; g < 4; ++g)
#pragma unroll
        for (int j = 0; j < 4; ++j)
          outv.h[g * 4 + j] = pv[j][g];
      __half* dst = C + ((((size_t)t * 4 + b_) * 8 + w_) * 2 + z_) * 1024 + l * 16;
      *(u32x4*)dst = outv.q[0];
      *(u32x4*)(dst + 8) = outv.q[1];
    }
  }
}

// ---------------- vq loss reduce (1024 threads) ----------------
__global__ __launch_bounds__(1024) void vq_reduce(const float* __restrict__ dmin,
                                                  float* __restrict__ out) {
  __shared__ float sh[1024];
  int tid = threadIdx.x;
  float s = 0.0f;
  for (int i = tid; i < Bb * Tt; i += 1024) s += dmin[i];
  sh[tid] = s;
  __syncthreads();
  for (int off = 512; off > 0; off >>= 1) {
    if (tid < off) sh[tid] += sh[tid + off];
    __syncthreads();
  }
  if (tid == 0) out[Bb * NCLS] = sh[0] * (1.25f / ((float)(Bb * Tt) * (float)Ee));
}

// ------ decoder backward, single step at t=T-1 via projB gather (bias baked) --
__global__ __launch_bounds__(256) void dec_bwd_last(const int* __restrict__ idx,
                                                    const float* __restrict__ projBf,
                                                    float* __restrict__ hb_last) {
  int b = blockIdx.x, tid = threadIdx.x;
  const int c = idx[(size_t)b * 512 + 511];
  const float* pr = projBf + (size_t)c * 1024;
  float a0 = pr[tid], a1 = pr[256 + tid], a2 = pr[512 + tid], a3 = pr[768 + tid];
  float i = sigf(a0), f = sigf(a1), g = tanhf(a2), o = sigf(a3);
  (void)f;
  float cc = i * g;
  hb_last[b * Hh + tid] = o * tanhf(cc);
}

// ---------------- classifier ----------------
__global__ __launch_bounds__(256) void classifier_k(const _Float16* __restrict__ hexD,
                                                    const float* __restrict__ hb_last,
                                                    const float* __restrict__ Wcls,
                                                    const float* __restrict__ bcls,
                                                    float* __restrict__ out) {
  int b = blockIdx.x, tid = threadIdx.x;
  __shared__ __align__(16) float dl[Ee];
  dl[tid] = (float)hexD[((size_t)(Tt - 1) * 64 + b) * 256 + tid];
  dl[tid + 256] = hb_last[b * Hh + tid];
  __syncthreads();
  if (tid < NCLS) {
    const float4* wr = (const float4*)(Wcls + (size_t)tid * Ee);
    float acc = bcls[tid];
#pragma unroll 4
    for (int e4 = 0; e4 < Ee / 4; ++e4) {
      float4 w = wr[e4];
      float4 z = *(const float4*)&dl[e4 * 4];
      acc = fmaf(w.x, z.x, acc);
      acc = fmaf(w.y, z.y, acc);
      acc = fmaf(w.z, z.z, acc);
      acc = fmaf(w.w, z.w, acc);
    }
    out[b * NCLS + tid] = acc;
  }
}

// ---------------- launch ----------------
extern "C" void kernel_launch(void* const* d_in, const int* in_sizes, int n_in,
                              void* d_out, int out_size, void* d_ws, size_t ws_size,
                              hipStream_t stream) {
  const float* x     = (const float*)d_in[0];
  const float* eWihF = (const float*)d_in[1];
  const float* eWhhF = (const float*)d_in[2];
  const float* ebF   = (const float*)d_in[3];
  const float* eWihB = (const float*)d_in[4];
  const float* eWhhB = (const float*)d_in[5];
  const float* ebB   = (const float*)d_in[6];
  const float* cb    = (const float*)d_in[7];
  const float* dWihF = (const float*)d_in[8];
  const float* dWhhF = (const float*)d_in[9];
  const float* dbF   = (const float*)d_in[10];
  const float* dWihB = (const float*)d_in[11];
  // d_in[12] = dec_Whh_b: unused (backward decoder state at t=T-1 starts from zero)
  const float* dbB   = (const float*)d_in[13];
  const float* Wcls  = (const float*)d_in[14];
  const float* bcls  = (const float*)d_in[15];
  float* out = (float*)d_out;
  float* w = (float*)d_ws;

  const size_t MR = (size_t)Bb * Tt;                 // 32768
  const size_t SZ_PRE_H = MR * G4 / 2;               // fp16 pre buffer, float units
  const size_t SZ_HEX  = (size_t)Tt * Bb * Hh / 2;   // fp16 exchange, float units
  const size_t SZ_XH   = MR * 256 / 2;               // xh fp16, float units
  const size_t SZ_WPH  = (size_t)G4 * Hh / 2;        // Whh frag pack, float units
  const size_t SZ_WIH  = (size_t)4 * 8 * 2 * 8 * 64 * 8 / 2;   // 131072 (enc, KS=8)
  const size_t SZ_PJF  = (size_t)NCODE * G4 / 2;     // projF fp16, float units
  const size_t SZ_PJB  = (size_t)NCODE * G4;         // projB fp32

  size_t o = 0;
  __half* preFh = (__half*)(w + o); o += SZ_PRE_H;
  __half* preBh = (__half*)(w + o); o += SZ_PRE_H;
  _Float16* hexF = (_Float16*)(w + o); o += SZ_HEX;
  _Float16* hexB = (_Float16*)(w + o); o += SZ_HEX;
  _Float16* hexD = (_Float16*)(w + o); o += SZ_HEX;
  _Float16* xh = (_Float16*)(w + o); o += SZ_XH;
  _Float16* wphF = (_Float16*)(w + o); o += SZ_WPH;
  _Float16* wphB = (_Float16*)(w + o); o += SZ_WPH;
  _Float16* wphD = (_Float16*)(w + o); o += SZ_WPH;
  _Float16* wpihF = (_Float16*)(w + o); o += SZ_WIH;
  _Float16* wpihB = (_Float16*)(w + o); o += SZ_WIH;
  _Float16* projFh = (_Float16*)(w + o); o += SZ_PJF;
  float* projBf = w + o; o += SZ_PJB;
  int* idxp = (int*)(w + o); o += MR;
  float* dminp = w + o; o += MR;
  float* hbl   = w + o; o += (size_t)Bb * Hh;
  // alias over dead region
  __half* dprf = preBh;               // dec fp16 pre over dead enc preB

  // 1. merged prep (one dispatch)
  hipLaunchKernelGGL(prep_all_k, dim3(51200), dim3(256), 0, stream,
                     (u32x4*)hexF, x, xh,
                     cb, dWihF, dbF, projFh, dWihB, dbB, projBf,
                     eWhhF, wphF, eWhhB, wphB, dWhhF, wphD,
                     eWihF, wpihF, eWihB, wpihB);

  // 2. encoder input projections (MFMA, both directions in one dispatch)
  hipLaunchKernelGGL(gemm_mfma_pre, dim3(Tt, 4, 2), dim3(256), 0, stream,
                     xh, wpihF, ebF, preFh, wpihB, ebB, preBh, 256);

  // 3. encoder scan: 128 one-wave blocks (64 fwd + 64 bwd)
  hipLaunchKernelGGL(lstm_scan_sync, dim3(128), dim3(64), 0, stream,
                     (const half8_t*)preFh, (const half8_t*)wphF, hexF,
                     (const half8_t*)preBh, (const half8_t*)wphB, hexB, 64);

  // 4. VQ (idx + dmin) + loss
  hipLaunchKernelGGL(vq_kernel, dim3((int)(MR / VPB)), dim3(128), 0, stream,
                     hexF, hexB, cb, idxp, dminp);
  hipLaunchKernelGGL(vq_reduce, dim3(1), dim3(1024), 0, stream, dminp, out);

  // 5. decoder fwd pre via per-code projection gather (replaces K=512 GEMM)
  hipLaunchKernelGGL(gather_pre_k, dim3(Tt), dim3(256), 0, stream,
                     idxp, projFh, dprf);

  // 6. decoder bwd (only t=T-1 contributes; projB gather)
  hipLaunchKernelGGL(dec_bwd_last, dim3(Bb), dim3(256), 0, stream, idxp, projBf, hbl);

  // 7. decoder fwd scan: 64 one-wave blocks
  hipLaunchKernelGGL(lstm_scan_sync, dim3(64), dim3(64), 0, stream,
                     (const half8_t*)dprf, (const half8_t*)wphD, hexD,
                     (const half8_t*)dprf, (const half8_t*)wphD, hexD, 64);

  // 8. classifier
  hipLaunchKernelGGL(classifier_k, dim3(Bb), dim3(256), 0, stream,
                     hexD, hbl, Wcls, bcls, out);
}